// Round 1
// baseline (9673.006 us; speedup 1.0000x reference)
//
#include <hip/hip_runtime.h>
#include <math.h>

// FullRankRNN scan: h_{t+1} = h + (0.05*noise + 0.2*inp@wi_full) + 0.2*(-h + tanh(h)@wrec^T)
// out_t = tanh(h_{t+1}) @ wo_full
// Design: one persistent block per batch (128 blocks x 512 threads). Thread j owns h[j]
// and column j of wrec^T. wrec^T cached: 72 rows LDS (144KB dynamic) + 128 rows VGPR,
// 312 rows streamed from L2. r=tanh(h) broadcast through LDS each step.

#define Bn 128
#define Tn 1000
#define In 4
#define Hn 512
#define On 2
#define ALPHA 0.2f
#define NSTD 0.05f

#define KC 72              // LDS-cached wrecT rows
#define KR 128             // register-cached wrecT rows
#define KS (Hn - KC - KR)  // 312 streamed rows (from L2)

__global__ void prep_kernel(const float* __restrict__ wi, const float* __restrict__ si,
                            const float* __restrict__ wrec, const float* __restrict__ wo,
                            const float* __restrict__ so,
                            float* __restrict__ wrecT, float* __restrict__ wi_full,
                            float* __restrict__ wo_full) {
    int idx = blockIdx.x * blockDim.x + threadIdx.x;
    int stride = gridDim.x * blockDim.x;
    // wrecT[k][j] = wrec[j][k]; enumerate output-major so WRITES are coalesced
    // (strided reads of wrec are absorbed by L2: 1 MB resident).
    for (int e = idx; e < Hn * Hn; e += stride) {
        int j = e & (Hn - 1);
        int k = e >> 9;
        wrecT[k * Hn + j] = wrec[j * Hn + k];
    }
    if (idx < In * Hn) wi_full[idx] = wi[idx] * si[idx >> 9];       // [I][H] * si[i]
    if (idx < Hn * On) wo_full[idx] = wo[idx] * so[idx & 1];        // [H][O] * so[o]
}

__global__ __launch_bounds__(512) void rnn_kernel(
    const float* __restrict__ input, const float* __restrict__ noise,
    const float* __restrict__ h0, const float* __restrict__ wrecT,
    const float* __restrict__ wi_full, const float* __restrict__ wo_full,
    float* __restrict__ out) {
    extern __shared__ float lds[];
    float* wlds = lds;                 // [KC][Hn]  cached wrecT rows
    float* r_s  = lds + KC * Hn;       // [Hn]      r = tanh(h) broadcast buffer
    float* red  = r_s + Hn;            // [16]      cross-wave output partials

    const int j = threadIdx.x;         // 0..511: owned state index
    const int b = blockIdx.x;          // batch

    // stage LDS wrec cache (coalesced, once)
    for (int k = 0; k < KC; ++k)
        wlds[k * Hn + j] = wrecT[k * Hn + j];

    // register wrec cache: rows [KC, KC+KR), column j (fully static indexing)
    float wreg[KR];
#pragma unroll
    for (int k = 0; k < KR; ++k)
        wreg[k] = wrecT[(KC + k) * Hn + j];

    const float wi0 = wi_full[j],          wi1 = wi_full[Hn + j],
                wi2 = wi_full[2 * Hn + j], wi3 = wi_full[3 * Hn + j];
    const float wo0 = wo_full[j * On], wo1 = wo_full[j * On + 1];

    float h = h0[j];
    r_s[j] = tanhf(h);
    __syncthreads();

    const float* __restrict__ noise_p = noise + (size_t)b * Tn * Hn + j;
    const float* __restrict__ inp_p   = input + (size_t)b * Tn * In;
    float*       __restrict__ out_p   = out   + (size_t)b * Tn * On;
    const float* __restrict__ wstr    = wrecT + (size_t)(KC + KR) * Hn + j;

    const int lane = j & 63;
    const int wid  = j >> 6;
    const float4* r4 = (const float4*)r_s;

    for (int t = 0; t < Tn; ++t) {
        float  nz  = noise_p[(size_t)t * Hn];                       // coalesced
        float4 inp = *(const float4*)(inp_p + t * In);              // uniform bcast

        // acc = sum_k r[k] * wrecT[k][j]; 4 accumulators break the FMA dep chain
        float a0 = 0.f, a1 = 0.f, a2 = 0.f, a3 = 0.f;

#pragma unroll 6
        for (int g = 0; g < KC / 4; ++g) {                          // LDS rows
            float4 rv = r4[g];
            const float* wp = wlds + 4 * g * Hn + j;
            a0 = fmaf(rv.x, wp[0],      a0);
            a1 = fmaf(rv.y, wp[Hn],     a1);
            a2 = fmaf(rv.z, wp[2 * Hn], a2);
            a3 = fmaf(rv.w, wp[3 * Hn], a3);
        }
#pragma unroll
        for (int g = 0; g < KR / 4; ++g) {                          // register rows
            float4 rv = r4[KC / 4 + g];
            a0 = fmaf(rv.x, wreg[4 * g + 0], a0);
            a1 = fmaf(rv.y, wreg[4 * g + 1], a1);
            a2 = fmaf(rv.z, wreg[4 * g + 2], a2);
            a3 = fmaf(rv.w, wreg[4 * g + 3], a3);
        }
#pragma unroll 4
        for (int g = 0; g < KS / 4; ++g) {                          // streamed rows (L2)
            float4 rv = r4[(KC + KR) / 4 + g];
            const float* wp = wstr + (size_t)4 * g * Hn;
            a0 = fmaf(rv.x, wp[0],      a0);
            a1 = fmaf(rv.y, wp[Hn],     a1);
            a2 = fmaf(rv.z, wp[2 * Hn], a2);
            a3 = fmaf(rv.w, wp[3 * Hn], a3);
        }
        float acc = (a0 + a1) + (a2 + a3);

        float drive = NSTD * nz +
                      ALPHA * (inp.x * wi0 + inp.y * wi1 + inp.z * wi2 + inp.w * wi3);
        h = h + drive + ALPHA * (acc - h);
        float rn = tanhf(h);

        // out[b,t,:] = sum_j rn_j * wo_full[j,:]  — wave shuffle + cross-wave LDS
        float p0 = rn * wo0, p1 = rn * wo1;
#pragma unroll
        for (int off = 32; off > 0; off >>= 1) {
            p0 += __shfl_down(p0, off, 64);
            p1 += __shfl_down(p1, off, 64);
        }

        __syncthreads();                 // all lanes done READING r_s for step t
        r_s[j] = rn;                     // publish r for step t+1
        if (lane == 0) { red[wid * 2] = p0; red[wid * 2 + 1] = p1; }
        __syncthreads();                 // r_s + red visible
        if (j == 0) {
            float s0 = 0.f, s1 = 0.f;
#pragma unroll
            for (int w = 0; w < 8; ++w) { s0 += red[2 * w]; s1 += red[2 * w + 1]; }
            out_p[t * On]     = s0;
            out_p[t * On + 1] = s1;
        }
    }
}

extern "C" void kernel_launch(void* const* d_in, const int* in_sizes, int n_in,
                              void* d_out, int out_size, void* d_ws, size_t ws_size,
                              hipStream_t stream) {
    const float* input = (const float*)d_in[0];
    const float* noise = (const float*)d_in[1];
    const float* wi    = (const float*)d_in[2];
    const float* si    = (const float*)d_in[3];
    const float* wrec  = (const float*)d_in[4];
    const float* wo    = (const float*)d_in[5];
    const float* so    = (const float*)d_in[6];
    const float* h0    = (const float*)d_in[7];
    float* out = (float*)d_out;

    // ws layout: wrecT (1 MB) | wi_full (8 KB) | wo_full (4 KB)  => needs ~1.04 MB
    float* wrecT   = (float*)d_ws;
    float* wi_full = wrecT + Hn * Hn;
    float* wo_full = wi_full + In * Hn;

    prep_kernel<<<512, 512, 0, stream>>>(wi, si, wrec, wo, so, wrecT, wi_full, wo_full);

    const size_t lds_bytes = (size_t)(KC * Hn + Hn + 16) * sizeof(float);  // ~146 KB
    hipFuncSetAttribute((const void*)rnn_kernel,
                        hipFuncAttributeMaxDynamicSharedMemorySize, (int)lds_bytes);
    rnn_kernel<<<Bn, Hn, lds_bytes, stream>>>(input, noise, h0, wrecT, wi_full,
                                              wo_full, out);
}